// Round 4
// baseline (610.788 us; speedup 1.0000x reference)
//
#include <hip/hip_runtime.h>
#include <hip/hip_bf16.h>
#include <math.h>

#define B_ 32
#define T_ 4096
#define D_ 512
#define U_ 512

typedef __bf16 bf16x8 __attribute__((ext_vector_type(8)));
typedef float floatx4 __attribute__((ext_vector_type(4)));
typedef unsigned short ushortx8 __attribute__((ext_vector_type(8)));

// exact RNE float -> bf16 (as uint) -- used in one-time W2 prep only
static __device__ __forceinline__ unsigned int f2bf(float f) {
  unsigned int u = __float_as_uint(f);
  return (u + 0x7fffu + ((u >> 16) & 1u)) >> 16;
}

// fast tanh: 1 - 2/(exp2(2x*log2e)+1). v_exp_f32 + v_rcp_f32; exact at +/-inf.
static __device__ __forceinline__ float tanh_fast(float x) {
  float e = exp2f(x * 2.88539008178f);
  return 1.0f - 2.0f * __builtin_amdgcn_rcpf(1.0f + e);
}

// pack 8 fp32 -> 8 bf16 (RNE) via compiler casts -> v_cvt_pk_bf16_f32
static __device__ __forceinline__ uint4 pack8(const float4 a, const float4 b) {
  bf16x8 v;
  v[0] = (__bf16)a.x; v[1] = (__bf16)a.y; v[2] = (__bf16)a.z; v[3] = (__bf16)a.w;
  v[4] = (__bf16)b.x; v[5] = (__bf16)b.y; v[6] = (__bf16)b.z; v[7] = (__bf16)b.w;
  return __builtin_bit_cast(uint4, v);
}

// ---------------------------------------------------------------------------
// P0: pack W2 (fp32 [k][u]) into MFMA-fragment-ordered bf16:
//   W2B[((ub*16 + kb)*64 + lane)*8 + j]
//     = bf16(W2[(kb*32 + (lane>>4)*8 + j)][ub*16 + (lane&15)])
// ---------------------------------------------------------------------------
__global__ __launch_bounds__(256) void prep_w2b(
    const float* __restrict__ W2, unsigned short* __restrict__ W2B) {
  const int s = blockIdx.x * 256 + threadIdx.x;  // slot id
  const int lane = s & 63;
  const int frag = s >> 6;       // 0..511
  const int ub = frag >> 4;      // u-block of 16
  const int kb = frag & 15;      // k-block of 32
  const int lr = lane & 15;
  const int kc = lane >> 4;
  const int u = ub * 16 + lr;
  const int k0 = kb * 32 + kc * 8;
  ushortx8 pk;
#pragma unroll
  for (int j = 0; j < 8; ++j)
    pk[j] = (unsigned short)f2bf(W2[(size_t)(k0 + j) * U_ + u]);
  *(ushortx8*)&W2B[(size_t)s * 8] = pk;
}

// ---------------------------------------------------------------------------
// K1: q_proj[b][u] = query[b]@W1[:,u] + b1[u] + b2[u]
// grid (B, 8) = 256 blocks; block = 64 u-cols x 4 k-quarters.
// ---------------------------------------------------------------------------
__global__ __launch_bounds__(256) void qproj_kernel(
    const float* __restrict__ query, const float* __restrict__ W1,
    const float* __restrict__ b1, const float* __restrict__ b2,
    float* __restrict__ qp) {
  const int b = blockIdx.x;
  const int ug = blockIdx.y;        // u-group of 64
  const int tid = threadIdx.x;
  const int uq = tid & 63;
  const int kq = tid >> 6;          // k-quarter 0..3
  __shared__ float qs[D_];
  __shared__ float red[4][64];
  qs[tid] = query[b * D_ + tid];
  qs[tid + 256] = query[b * D_ + tid + 256];
  __syncthreads();
  const int u = ug * 64 + uq;
  float a = 0.f;
#pragma unroll 8
  for (int k = kq * 128; k < kq * 128 + 128; ++k)
    a += qs[k] * W1[(size_t)k * U_ + u];
  red[kq][uq] = a;
  __syncthreads();
  if (tid < 64) {
    const int uu = ug * 64 + tid;
    qp[b * U_ + uu] =
        red[0][tid] + red[1][tid] + red[2][tid] + red[3][tid] + b1[uu] + b2[uu];
  }
}

// ---------------------------------------------------------------------------
// K2: streaming scores + FUSED context accumulation.
// 256 blocks (one per CU), 512 threads = 8 waves (u-split 64/wave). Each
// block owns 8 consecutive 64-row t-tiles of one batch (1 MB contiguous
// values). Double-buffered bf16 A-tile (2 x 64 KB, XOR swizzle). Prefetch is
// two batches of 8 float4 (32 VGPRs each). Epilogue: w_t = exp(score_t),
// fused num/den accumulation from the LDS tile (no separate context pass).
//
// __launch_bounds__(512, 1): min-1-wave/EU gives the allocator the full
// register budget. Rounds 2-3 spilled (WRITE_SIZE 97/336 MB of scratch):
// the default heuristic targeted 128 VGPRs. Occupancy is unchanged by the
// bigger register budget -- 132 KB LDS already pins 1 block/CU (2 waves/EU).
// ---------------------------------------------------------------------------
__global__ __launch_bounds__(512, 1)
void scores_mfma(const float* __restrict__ values,
                 const unsigned short* __restrict__ W2B,
                 const float* __restrict__ qp, const float* __restrict__ V,
                 float* __restrict__ num, float* __restrict__ den) {
  __shared__ __align__(16) unsigned short As[2 * 64 * 512];  // 128 KB
  __shared__ float redp[2 * 512];                            // [parity][w][row]

  const int b = blockIdx.y;
  const int tg = blockIdx.x;          // t-group: 512 rows
  const int tid = threadIdx.x;
  const int w = tid >> 6;             // wave 0..7
  const int lane = tid & 63;
  const int lr = lane & 15;           // fragment row within 16
  const int kc = lane >> 4;           // k-chunk 0..3 (8 bf16 each)
  const int w4 = w * 4;
  const int cw = lane ^ w;            // staging granule (wave w stages rows r&7==w)

  const float* vbase = values + ((size_t)b * T_ + (size_t)tg * 512) * D_;
  const ushortx8* W2Bv = (const ushortx8*)W2B;

  // per-wave u-slice constants: u = w*64 + j*16 + lr
  float qv[4], vv[4];
  const float* qpb = qp + b * U_;
#pragma unroll
  for (int j = 0; j < 4; ++j) {
    const int u = w * 64 + j * 16 + lr;
    qv[j] = qpb[u];
    vv[j] = V[u];
  }

  // fused-context accumulators: lane owns d-chunk (w*8 + (lane&7)), 8 floats
  float wacc[8];
#pragma unroll
  for (int d = 0; d < 8; ++d) wacc[d] = 0.f;
  float denl = 0.f;  // wave 0: per-lane (=per-row) weight accumulator

  // ---- prologue: stage tile 0 into buffer 0 (two 32-reg batches) ----
#pragma unroll
  for (int h = 0; h < 2; ++h) {
    float4 pv[8];
#pragma unroll
    for (int p = 0; p < 4; ++p) {
      const int r = (h * 4 + p) * 8 + w;
      const float* rp = vbase + (size_t)r * D_ + lane * 8;
      pv[2 * p] = *(const float4*)rp;
      pv[2 * p + 1] = *(const float4*)(rp + 4);
    }
#pragma unroll
    for (int p = 0; p < 4; ++p) {
      const int r = (h * 4 + p) * 8 + w;
      *(uint4*)&As[r * 512 + cw * 8] = pack8(pv[2 * p], pv[2 * p + 1]);
    }
  }
  __syncthreads();

  for (int n = 0; n < 8; ++n) {
    const int cur = n & 1;
    const unsigned short* Asc = As + cur * 32768;
    unsigned short* Asn = As + (cur ^ 1) * 32768;
    const float* tb = vbase + (size_t)(n + 1) * 64 * D_;

    floatx4 acc[4][4];
#pragma unroll
    for (int i = 0; i < 4; ++i)
#pragma unroll
      for (int j = 0; j < 4; ++j) acc[i][j] = (floatx4)0.f;

    // 1a. issue prefetch batch A (rows 0..31 of tile n+1) -- 32 VGPRs
    float4 sv[8];
    if (n < 7) {
#pragma unroll
      for (int p = 0; p < 4; ++p) {
        const float* rp = tb + (size_t)(p * 8 + w) * D_ + lane * 8;
        sv[2 * p] = *(const float4*)rp;
        sv[2 * p + 1] = *(const float4*)(rp + 4);
      }
    }

    // 2a. K-loop first half (no barriers)
#pragma unroll
    for (int ks = 0; ks < 8; ++ks) {
      bf16x8 bfr[4];
#pragma unroll
      for (int j = 0; j < 4; ++j)
        bfr[j] = __builtin_bit_cast(bf16x8,
                                    W2Bv[((w4 + j) * 16 + ks) * 64 + lane]);
      const int c = (ks * 4 + kc) ^ (lr & 7);   // row ri&7 == lr&7 for all i
      bf16x8 af[4];
#pragma unroll
      for (int i = 0; i < 4; ++i)
        af[i] = __builtin_bit_cast(
            bf16x8, *(const ushortx8*)&Asc[(i * 16 + lr) * 512 + c * 8]);
#pragma unroll
      for (int i = 0; i < 4; ++i)
#pragma unroll
        for (int j = 0; j < 4; ++j)
          acc[i][j] = __builtin_amdgcn_mfma_f32_16x16x32_bf16(
              af[i], bfr[j], acc[i][j], 0, 0, 0);
    }

    // 1b. write batch A to LDS (buffer cur^1), issue batch B
    if (n < 7) {
#pragma unroll
      for (int p = 0; p < 4; ++p) {
        const int r = p * 8 + w;
        *(uint4*)&Asn[r * 512 + cw * 8] = pack8(sv[2 * p], sv[2 * p + 1]);
      }
#pragma unroll
      for (int p = 0; p < 4; ++p) {
        const float* rp = tb + (size_t)((p + 4) * 8 + w) * D_ + lane * 8;
        sv[2 * p] = *(const float4*)rp;
        sv[2 * p + 1] = *(const float4*)(rp + 4);
      }
    }

    // 2b. K-loop second half
#pragma unroll
    for (int ks = 8; ks < 16; ++ks) {
      bf16x8 bfr[4];
#pragma unroll
      for (int j = 0; j < 4; ++j)
        bfr[j] = __builtin_bit_cast(bf16x8,
                                    W2Bv[((w4 + j) * 16 + ks) * 64 + lane]);
      const int c = (ks * 4 + kc) ^ (lr & 7);
      bf16x8 af[4];
#pragma unroll
      for (int i = 0; i < 4; ++i)
        af[i] = __builtin_bit_cast(
            bf16x8, *(const ushortx8*)&Asc[(i * 16 + lr) * 512 + c * 8]);
#pragma unroll
      for (int i = 0; i < 4; ++i)
#pragma unroll
        for (int j = 0; j < 4; ++j)
          acc[i][j] = __builtin_amdgcn_mfma_f32_16x16x32_bf16(
              af[i], bfr[j], acc[i][j], 0, 0, 0);
    }

    // 3. epilogue partials: C/D layout u = w*64+j*16+lr, t = i*16+kc*4+r
#pragma unroll
    for (int i = 0; i < 4; ++i) {
#pragma unroll
      for (int r = 0; r < 4; ++r) {
        float s = 0.f;
#pragma unroll
        for (int j = 0; j < 4; ++j) s += tanh_fast(acc[i][j][r] + qv[j]) * vv[j];
        s += __shfl_xor(s, 1);
        s += __shfl_xor(s, 2);
        s += __shfl_xor(s, 4);
        s += __shfl_xor(s, 8);
        if (lr == 0) redp[cur * 512 + w * 64 + i * 16 + kc * 4 + r] = s;
      }
    }

    // 1c. write batch B to LDS
    if (n < 7) {
#pragma unroll
      for (int p = 0; p < 4; ++p) {
        const int r = (p + 4) * 8 + w;
        *(uint4*)&Asn[r * 512 + cw * 8] = pack8(sv[2 * p], sv[2 * p + 1]);
      }
    }

    __syncthreads();  // b1: redp + next-tile writes visible; cur reads done

    // 4. per-row weight (row = lane), computed redundantly by every wave
    float sw = redp[cur * 512 + lane];
#pragma unroll
    for (int p = 1; p < 8; ++p) sw += redp[cur * 512 + p * 64 + lane];
    const float wgt = expf(sw);
    if (w == 0) denl += wgt;

    // 5. fused context: wacc[d] += w_r * v[r][d] from the bf16 tile in LDS.
    // lane covers chunk (w*8 + (lane&7)); rows r = (lane>>3) + 8*jj.
#pragma unroll
    for (int jj = 0; jj < 8; ++jj) {
      const int r = (lane >> 3) + 8 * jj;     // r&7 == lane>>3
      const float wr = __shfl(wgt, r);
      const int g = (w * 8 + (lane & 7)) ^ (lane >> 3);
      const ushortx8 vx = *(const ushortx8*)&Asc[r * 512 + g * 8];
#pragma unroll
      for (int d = 0; d < 8; ++d)
        wacc[d] += wr * __uint_as_float((unsigned)vx[d] << 16);
    }

    __syncthreads();  // b2: wsum reads of cur done before n+1 overwrites cur
  }

  // ---- final: reduce wacc over the 8 row-subsets, atomically accumulate ----
#pragma unroll
  for (int d = 0; d < 8; ++d) {
    wacc[d] += __shfl_xor(wacc[d], 8);
    wacc[d] += __shfl_xor(wacc[d], 16);
    wacc[d] += __shfl_xor(wacc[d], 32);
  }
  if (lane < 8) {
    const int d0 = (w * 8 + lane) * 8;
#pragma unroll
    for (int d = 0; d < 8; ++d) atomicAdd(&num[b * D_ + d0 + d], wacc[d]);
  }
  if (w == 0) {
#pragma unroll
    for (int off = 1; off < 64; off <<= 1) denl += __shfl_xor(denl, off);
    if (lane == 0) atomicAdd(&den[b], denl);
  }
}

// ---------------------------------------------------------------------------
// K3: out[b][d] = num[b][d] / den[b]
// ---------------------------------------------------------------------------
__global__ __launch_bounds__(128) void normalize_kernel(
    const float* __restrict__ num, const float* __restrict__ den,
    float* __restrict__ out) {
  const int b = blockIdx.x;
  const float inv = 1.0f / den[b];
  const int d = threadIdx.x * 4;
  float4 v = *(const float4*)&num[b * D_ + d];
  v.x *= inv;
  v.y *= inv;
  v.z *= inv;
  v.w *= inv;
  *(float4*)&out[b * D_ + d] = v;
}

// ---------------------------------------------------------------------------
extern "C" void kernel_launch(void* const* d_in, const int* in_sizes, int n_in,
                              void* d_out, int out_size, void* d_ws,
                              size_t ws_size, hipStream_t stream) {
  const float* query = (const float*)d_in[0];
  const float* values = (const float*)d_in[1];
  const float* W1 = (const float*)d_in[2];
  const float* b1 = (const float*)d_in[3];
  const float* W2 = (const float*)d_in[4];
  const float* b2 = (const float*)d_in[5];
  const float* V = (const float*)d_in[6];
  // d_in[7] = bv : dropped (softmax shift-invariant; cancels in context)

  // ws layout: qp (64 KB) | W2B bf16 packed (512 KB) | num (64 KB) | den (128 B)
  float* qp = (float*)d_ws;
  unsigned short* W2B = (unsigned short*)(qp + (size_t)B_ * U_);
  float* num = (float*)(W2B + (size_t)U_ * D_);
  float* den = num + (size_t)B_ * D_;
  float* out = (float*)d_out;

  (void)hipMemsetAsync(num, 0, ((size_t)B_ * D_ + B_) * sizeof(float), stream);

  prep_w2b<<<128, 256, 0, stream>>>(W2, W2B);
  qproj_kernel<<<dim3(B_, 8), 256, 0, stream>>>(query, W1, b1, b2, qp);
  scores_mfma<<<dim3(8, B_), 512, 0, stream>>>(values, W2B, qp, V, num, den);
  normalize_kernel<<<B_, 128, 0, stream>>>(num, den, out);
}

// Round 5
// 558.984 us; speedup vs baseline: 1.0927x; 1.0927x over previous
//
#include <hip/hip_runtime.h>
#include <hip/hip_bf16.h>
#include <math.h>

#define B_ 32
#define T_ 4096
#define D_ 512
#define U_ 512

typedef __bf16 bf16x8 __attribute__((ext_vector_type(8)));
typedef float floatx4 __attribute__((ext_vector_type(4)));
typedef unsigned short ushortx8 __attribute__((ext_vector_type(8)));

// exact RNE float -> bf16 (as uint) -- used in one-time W2 prep only
static __device__ __forceinline__ unsigned int f2bf(float f) {
  unsigned int u = __float_as_uint(f);
  return (u + 0x7fffu + ((u >> 16) & 1u)) >> 16;
}

// fast tanh: 1 - 2/(exp2(2x*log2e)+1). v_exp_f32 + v_rcp_f32; exact at +/-inf.
static __device__ __forceinline__ float tanh_fast(float x) {
  float e = exp2f(x * 2.88539008178f);
  return 1.0f - 2.0f * __builtin_amdgcn_rcpf(1.0f + e);
}

// pack 8 fp32 -> 8 bf16 (RNE) via compiler casts -> v_cvt_pk_bf16_f32
static __device__ __forceinline__ uint4 pack8(const float4 a, const float4 b) {
  bf16x8 v;
  v[0] = (__bf16)a.x; v[1] = (__bf16)a.y; v[2] = (__bf16)a.z; v[3] = (__bf16)a.w;
  v[4] = (__bf16)b.x; v[5] = (__bf16)b.y; v[6] = (__bf16)b.z; v[7] = (__bf16)b.w;
  return __builtin_bit_cast(uint4, v);
}

// ---------------------------------------------------------------------------
// P0: pack W2 (fp32 [k][u]) into MFMA-fragment-ordered bf16:
//   W2B[((ub*16 + kb)*64 + lane)*8 + j]
//     = bf16(W2[(kb*32 + (lane>>4)*8 + j)][ub*16 + (lane&15)])
// ---------------------------------------------------------------------------
__global__ __launch_bounds__(256) void prep_w2b(
    const float* __restrict__ W2, unsigned short* __restrict__ W2B) {
  const int s = blockIdx.x * 256 + threadIdx.x;  // slot id
  const int lane = s & 63;
  const int frag = s >> 6;       // 0..511
  const int ub = frag >> 4;      // u-block of 16
  const int kb = frag & 15;      // k-block of 32
  const int lr = lane & 15;
  const int kc = lane >> 4;
  const int u = ub * 16 + lr;
  const int k0 = kb * 32 + kc * 8;
  ushortx8 pk;
#pragma unroll
  for (int j = 0; j < 8; ++j)
    pk[j] = (unsigned short)f2bf(W2[(size_t)(k0 + j) * U_ + u]);
  *(ushortx8*)&W2B[(size_t)s * 8] = pk;
}

// ---------------------------------------------------------------------------
// K1: q_proj[b][u] = query[b]@W1[:,u] + b1[u] + b2[u]
// grid (B, 8) = 256 blocks; block = 64 u-cols x 4 k-quarters.
// ---------------------------------------------------------------------------
__global__ __launch_bounds__(256) void qproj_kernel(
    const float* __restrict__ query, const float* __restrict__ W1,
    const float* __restrict__ b1, const float* __restrict__ b2,
    float* __restrict__ qp) {
  const int b = blockIdx.x;
  const int ug = blockIdx.y;        // u-group of 64
  const int tid = threadIdx.x;
  const int uq = tid & 63;
  const int kq = tid >> 6;          // k-quarter 0..3
  __shared__ float qs[D_];
  __shared__ float red[4][64];
  qs[tid] = query[b * D_ + tid];
  qs[tid + 256] = query[b * D_ + tid + 256];
  __syncthreads();
  const int u = ug * 64 + uq;
  float a = 0.f;
#pragma unroll 8
  for (int k = kq * 128; k < kq * 128 + 128; ++k)
    a += qs[k] * W1[(size_t)k * U_ + u];
  red[kq][uq] = a;
  __syncthreads();
  if (tid < 64) {
    const int uu = ug * 64 + tid;
    qp[b * U_ + uu] =
        red[0][tid] + red[1][tid] + red[2][tid] + red[3][tid] + b1[uu] + b2[uu];
  }
}

// ---------------------------------------------------------------------------
// K2: streaming scores + FUSED context accumulation.
// 256 blocks (one per CU), 512 threads = 8 waves (u-split 64/wave). Each
// block owns 8 consecutive 64-row t-tiles of one batch. Double-buffered bf16
// A-tile (2 x 64 KB, XOR swizzle).
//
// SPILL FIX (rounds 2-4 post-mortem): the allocator pins arch-VGPRs at 128
// for this kernel (attributes don't move it); the old 32-reg prefetch put
// arch-live at ~170 -> ~40 regs spilled -> 336 MB scratch WRITE + 309 MB
// re-FETCH per dispatch. Staging is now FOUR phases interleaved with the
// four quarters of the K-loop: issue 4 float4 (2 rows, 16 regs) -> 64 MFMA
// quarter (~300 cyc, hides load latency; co-resident wave hides the rest)
// -> pack+write those 2 rows. Named scalars s0..s3, all compile-time
// indices. Arch-live ~95 < 128 -> no spill.
//
// Epilogue: w_t = exp(score_t) (|s|<=~8, fp32-safe), fused num/den
// accumulation from the LDS tile (no separate context pass). Two barriers
// per tile.
// ---------------------------------------------------------------------------
__global__ __launch_bounds__(512, 1)
void scores_mfma(const float* __restrict__ values,
                 const unsigned short* __restrict__ W2B,
                 const float* __restrict__ qp, const float* __restrict__ V,
                 float* __restrict__ num, float* __restrict__ den) {
  __shared__ __align__(16) unsigned short As[2 * 64 * 512];  // 128 KB
  __shared__ float redp[2 * 512];                            // [parity][w][row]

  const int b = blockIdx.y;
  const int tg = blockIdx.x;          // t-group: 512 rows
  const int tid = threadIdx.x;
  const int w = tid >> 6;             // wave 0..7
  const int lane = tid & 63;
  const int lr = lane & 15;           // fragment row within 16
  const int kc = lane >> 4;           // k-chunk 0..3 (8 bf16 each)
  const int w4 = w * 4;
  const int cw = lane ^ w;            // staging granule (wave w stages rows r&7==w)

  const float* vbase = values + ((size_t)b * T_ + (size_t)tg * 512) * D_;
  const ushortx8* W2Bv = (const ushortx8*)W2B;

  // per-wave u-slice constants: u = w*64 + j*16 + lr
  float qv[4], vv[4];
  const float* qpb = qp + b * U_;
#pragma unroll
  for (int j = 0; j < 4; ++j) {
    const int u = w * 64 + j * 16 + lr;
    qv[j] = qpb[u];
    vv[j] = V[u];
  }

  // fused-context accumulators: lane owns d-chunk (w*8 + (lane&7)), 8 floats
  float wacc[8];
#pragma unroll
  for (int d = 0; d < 8; ++d) wacc[d] = 0.f;
  float denl = 0.f;  // wave 0: per-lane (=per-row) weight accumulator

  // ---- prologue: stage tile 0 into buffer 0 (4 batches of 2 rows) ----
#pragma unroll
  for (int p = 0; p < 4; ++p) {
    const int r0 = (2 * p) * 8 + w;
    const int r1 = (2 * p + 1) * 8 + w;
    const float* rp0 = vbase + (size_t)r0 * D_ + lane * 8;
    const float* rp1 = vbase + (size_t)r1 * D_ + lane * 8;
    const float4 s0 = *(const float4*)rp0;
    const float4 s1 = *(const float4*)(rp0 + 4);
    const float4 s2 = *(const float4*)rp1;
    const float4 s3 = *(const float4*)(rp1 + 4);
    *(uint4*)&As[r0 * 512 + cw * 8] = pack8(s0, s1);
    *(uint4*)&As[r1 * 512 + cw * 8] = pack8(s2, s3);
  }
  __syncthreads();

  for (int n = 0; n < 8; ++n) {
    const int cur = n & 1;
    const unsigned short* Asc = As + cur * 32768;
    unsigned short* Asn = As + (cur ^ 1) * 32768;
    const float* tb = vbase + (size_t)(n + 1) * 64 * D_;
    const bool pf = (n < 7);

    floatx4 acc[4][4];
#pragma unroll
    for (int i = 0; i < 4; ++i)
#pragma unroll
      for (int j = 0; j < 4; ++j) acc[i][j] = (floatx4)0.f;

    // ---- 4 phases: {issue 2-row prefetch | K-quarter | write 2 rows} ----
#pragma unroll
    for (int p = 0; p < 4; ++p) {
      const int r0 = (2 * p) * 8 + w;
      const int r1 = (2 * p + 1) * 8 + w;
      float4 s0, s1, s2, s3;
      if (pf) {
        const float* rp0 = tb + (size_t)r0 * D_ + lane * 8;
        const float* rp1 = tb + (size_t)r1 * D_ + lane * 8;
        s0 = *(const float4*)rp0;
        s1 = *(const float4*)(rp0 + 4);
        s2 = *(const float4*)rp1;
        s3 = *(const float4*)(rp1 + 4);
      }

      // K-quarter: ks = 4p .. 4p+3
#pragma unroll
      for (int kq = 0; kq < 4; ++kq) {
        const int ks = p * 4 + kq;
        bf16x8 bfr[4];
#pragma unroll
        for (int j = 0; j < 4; ++j)
          bfr[j] = __builtin_bit_cast(bf16x8,
                                      W2Bv[((w4 + j) * 16 + ks) * 64 + lane]);
        const int c = (ks * 4 + kc) ^ (lr & 7);   // row ri&7 == lr&7 for all i
        bf16x8 af[4];
#pragma unroll
        for (int i = 0; i < 4; ++i)
          af[i] = __builtin_bit_cast(
              bf16x8, *(const ushortx8*)&Asc[(i * 16 + lr) * 512 + c * 8]);
#pragma unroll
        for (int i = 0; i < 4; ++i)
#pragma unroll
          for (int j = 0; j < 4; ++j)
            acc[i][j] = __builtin_amdgcn_mfma_f32_16x16x32_bf16(
                af[i], bfr[j], acc[i][j], 0, 0, 0);
      }

      if (pf) {
        *(uint4*)&Asn[r0 * 512 + cw * 8] = pack8(s0, s1);
        *(uint4*)&Asn[r1 * 512 + cw * 8] = pack8(s2, s3);
      }
    }

    // epilogue partials: C/D layout u = w*64+j*16+lr, t = i*16+kc*4+r
#pragma unroll
    for (int i = 0; i < 4; ++i) {
#pragma unroll
      for (int r = 0; r < 4; ++r) {
        float s = 0.f;
#pragma unroll
        for (int j = 0; j < 4; ++j) s += tanh_fast(acc[i][j][r] + qv[j]) * vv[j];
        s += __shfl_xor(s, 1);
        s += __shfl_xor(s, 2);
        s += __shfl_xor(s, 4);
        s += __shfl_xor(s, 8);
        if (lr == 0) redp[cur * 512 + w * 64 + i * 16 + kc * 4 + r] = s;
      }
    }

    __syncthreads();  // b1: redp + next-tile writes visible; cur reads done

    // per-row weight (row = lane), computed redundantly by every wave
    float sw = redp[cur * 512 + lane];
#pragma unroll
    for (int p = 1; p < 8; ++p) sw += redp[cur * 512 + p * 64 + lane];
    const float wgt = expf(sw);
    if (w == 0) denl += wgt;

    // fused context: wacc[d] += w_r * v[r][d] from the bf16 tile in LDS.
    // lane covers chunk (w*8 + (lane&7)); rows r = (lane>>3) + 8*jj.
#pragma unroll
    for (int jj = 0; jj < 8; ++jj) {
      const int r = (lane >> 3) + 8 * jj;     // r&7 == lane>>3
      const float wr = __shfl(wgt, r);
      const int g = (w * 8 + (lane & 7)) ^ (lane >> 3);
      const ushortx8 vx = *(const ushortx8*)&Asc[r * 512 + g * 8];
#pragma unroll
      for (int d = 0; d < 8; ++d)
        wacc[d] += wr * __uint_as_float((unsigned)vx[d] << 16);
    }

    __syncthreads();  // b2: wsum reads of cur done before n+1 overwrites cur
  }

  // ---- final: reduce wacc over the 8 row-subsets, atomically accumulate ----
#pragma unroll
  for (int d = 0; d < 8; ++d) {
    wacc[d] += __shfl_xor(wacc[d], 8);
    wacc[d] += __shfl_xor(wacc[d], 16);
    wacc[d] += __shfl_xor(wacc[d], 32);
  }
  if (lane < 8) {
    const int d0 = (w * 8 + lane) * 8;
#pragma unroll
    for (int d = 0; d < 8; ++d) atomicAdd(&num[b * D_ + d0 + d], wacc[d]);
  }
  if (w == 0) {
#pragma unroll
    for (int off = 1; off < 64; off <<= 1) denl += __shfl_xor(denl, off);
    if (lane == 0) atomicAdd(&den[b], denl);
  }
}

// ---------------------------------------------------------------------------
// K3: out[b][d] = num[b][d] / den[b]
// ---------------------------------------------------------------------------
__global__ __launch_bounds__(128) void normalize_kernel(
    const float* __restrict__ num, const float* __restrict__ den,
    float* __restrict__ out) {
  const int b = blockIdx.x;
  const float inv = 1.0f / den[b];
  const int d = threadIdx.x * 4;
  float4 v = *(const float4*)&num[b * D_ + d];
  v.x *= inv;
  v.y *= inv;
  v.z *= inv;
  v.w *= inv;
  *(float4*)&out[b * D_ + d] = v;
}

// ---------------------------------------------------------------------------
extern "C" void kernel_launch(void* const* d_in, const int* in_sizes, int n_in,
                              void* d_out, int out_size, void* d_ws,
                              size_t ws_size, hipStream_t stream) {
  const float* query = (const float*)d_in[0];
  const float* values = (const float*)d_in[1];
  const float* W1 = (const float*)d_in[2];
  const float* b1 = (const float*)d_in[3];
  const float* W2 = (const float*)d_in[4];
  const float* b2 = (const float*)d_in[5];
  const float* V = (const float*)d_in[6];
  // d_in[7] = bv : dropped (softmax shift-invariant; cancels in context)

  // ws layout: qp (64 KB) | W2B bf16 packed (512 KB) | num (64 KB) | den (128 B)
  float* qp = (float*)d_ws;
  unsigned short* W2B = (unsigned short*)(qp + (size_t)B_ * U_);
  float* num = (float*)(W2B + (size_t)U_ * D_);
  float* den = num + (size_t)B_ * D_;
  float* out = (float*)d_out;

  (void)hipMemsetAsync(num, 0, ((size_t)B_ * D_ + B_) * sizeof(float), stream);

  prep_w2b<<<128, 256, 0, stream>>>(W2, W2B);
  qproj_kernel<<<dim3(B_, 8), 256, 0, stream>>>(query, W1, b1, b2, qp);
  scores_mfma<<<dim3(8, B_), 512, 0, stream>>>(values, W2B, qp, V, num, den);
  normalize_kernel<<<B_, 128, 0, stream>>>(num, den, out);
}

// Round 6
// 520.280 us; speedup vs baseline: 1.1740x; 1.0744x over previous
//
#include <hip/hip_runtime.h>
#include <hip/hip_bf16.h>
#include <math.h>

#define B_ 32
#define T_ 4096
#define D_ 512
#define U_ 512

typedef __bf16 bf16x8 __attribute__((ext_vector_type(8)));
typedef float floatx4 __attribute__((ext_vector_type(4)));
typedef unsigned short ushortx8 __attribute__((ext_vector_type(8)));

// exact RNE float -> bf16 (as uint) -- used in one-time W2 prep only
static __device__ __forceinline__ unsigned int f2bf(float f) {
  unsigned int u = __float_as_uint(f);
  return (u + 0x7fffu + ((u >> 16) & 1u)) >> 16;
}

// fast tanh: 1 - 2/(exp2(2x*log2e)+1). v_exp_f32 + v_rcp_f32; exact at +/-inf.
static __device__ __forceinline__ float tanh_fast(float x) {
  float e = exp2f(x * 2.88539008178f);
  return 1.0f - 2.0f * __builtin_amdgcn_rcpf(1.0f + e);
}

// pack 8 fp32 -> 8 bf16 (RNE) via compiler casts -> v_cvt_pk_bf16_f32
static __device__ __forceinline__ uint4 pack8(const float4 a, const float4 b) {
  bf16x8 v;
  v[0] = (__bf16)a.x; v[1] = (__bf16)a.y; v[2] = (__bf16)a.z; v[3] = (__bf16)a.w;
  v[4] = (__bf16)b.x; v[5] = (__bf16)b.y; v[6] = (__bf16)b.z; v[7] = (__bf16)b.w;
  return __builtin_bit_cast(uint4, v);
}

// ---------------------------------------------------------------------------
// P0: pack W2 (fp32 [k][u]) into MFMA-fragment-ordered bf16:
//   W2B[((ub*16 + kb)*64 + lane)*8 + j]
//     = bf16(W2[(kb*32 + (lane>>4)*8 + j)][ub*16 + (lane&15)])
// ---------------------------------------------------------------------------
__global__ __launch_bounds__(256) void prep_w2b(
    const float* __restrict__ W2, unsigned short* __restrict__ W2B) {
  const int s = blockIdx.x * 256 + threadIdx.x;  // slot id
  const int lane = s & 63;
  const int frag = s >> 6;       // 0..511
  const int ub = frag >> 4;      // u-block of 16
  const int kb = frag & 15;      // k-block of 32
  const int lr = lane & 15;
  const int kc = lane >> 4;
  const int u = ub * 16 + lr;
  const int k0 = kb * 32 + kc * 8;
  ushortx8 pk;
#pragma unroll
  for (int j = 0; j < 8; ++j)
    pk[j] = (unsigned short)f2bf(W2[(size_t)(k0 + j) * U_ + u]);
  *(ushortx8*)&W2B[(size_t)s * 8] = pk;
}

// ---------------------------------------------------------------------------
// K1: q_proj[b][u] = query[b]@W1[:,u] + b1[u] + b2[u]
// grid (B, 8) = 256 blocks; block = 64 u-cols x 4 k-quarters.
// ---------------------------------------------------------------------------
__global__ __launch_bounds__(256) void qproj_kernel(
    const float* __restrict__ query, const float* __restrict__ W1,
    const float* __restrict__ b1, const float* __restrict__ b2,
    float* __restrict__ qp) {
  const int b = blockIdx.x;
  const int ug = blockIdx.y;        // u-group of 64
  const int tid = threadIdx.x;
  const int uq = tid & 63;
  const int kq = tid >> 6;          // k-quarter 0..3
  __shared__ float qs[D_];
  __shared__ float red[4][64];
  qs[tid] = query[b * D_ + tid];
  qs[tid + 256] = query[b * D_ + tid + 256];
  __syncthreads();
  const int u = ug * 64 + uq;
  float a = 0.f;
#pragma unroll 8
  for (int k = kq * 128; k < kq * 128 + 128; ++k)
    a += qs[k] * W1[(size_t)k * U_ + u];
  red[kq][uq] = a;
  __syncthreads();
  if (tid < 64) {
    const int uu = ug * 64 + tid;
    qp[b * U_ + uu] =
        red[0][tid] + red[1][tid] + red[2][tid] + red[3][tid] + b1[uu] + b2[uu];
  }
}

// ---------------------------------------------------------------------------
// K2: streaming scores + FUSED context accumulation.
// 256 blocks (one per CU), 512 threads = 8 waves (u-split 64/wave). Each
// block owns 8 consecutive 64-row t-tiles of one batch. Double-buffered bf16
// A-tile (2 x 64 KB, XOR swizzle).
//
// SPILL FIX v2 (round-5 post-mortem): 100 MB of scratch writes remained
// after shrinking the staging set -- the spill is SCHEDULER-created
// liveness: fully-unrolled phase/ks loops let the scheduler hoist all 16
// W2Bv B-frag loads (64 VGPRs) plus next-phase staging loads past the
// MFMAs. Fix: phase loop and ks loop are runtime loops (#pragma unroll 1)
// -- nothing can be hoisted across a back-edge -- and bfr[j] is loaded
// immediately before its 4 MFMAs. acc/af keep static indexing (AGPR-safe).
// Latency-hiding loss is irrelevant: compute has ~5x slack vs the HBM
// stream (2.6k cyc/tile vs 12.5k cyc), and 2 waves/SIMD co-schedule.
//
// Epilogue: w_t = exp(score_t) (|s|<=~8, fp32-safe), fused num/den
// accumulation from the LDS tile (no separate context pass). Two barriers
// per tile.
// ---------------------------------------------------------------------------
__global__ __launch_bounds__(512, 1)
void scores_mfma(const float* __restrict__ values,
                 const unsigned short* __restrict__ W2B,
                 const float* __restrict__ qp, const float* __restrict__ V,
                 float* __restrict__ num, float* __restrict__ den) {
  __shared__ __align__(16) unsigned short As[2 * 64 * 512];  // 128 KB
  __shared__ float redp[2 * 512];                            // [parity][w][row]

  const int b = blockIdx.y;
  const int tg = blockIdx.x;          // t-group: 512 rows
  const int tid = threadIdx.x;
  const int w = tid >> 6;             // wave 0..7
  const int lane = tid & 63;
  const int lr = lane & 15;           // fragment row within 16
  const int kc = lane >> 4;           // k-chunk 0..3 (8 bf16 each)
  const int w4 = w * 4;
  const int cw = lane ^ w;            // staging granule (wave w stages rows r&7==w)

  const float* vbase = values + ((size_t)b * T_ + (size_t)tg * 512) * D_;
  const ushortx8* W2Bv = (const ushortx8*)W2B;

  // per-wave u-slice constants: u = w*64 + j*16 + lr
  float qv[4], vv[4];
  const float* qpb = qp + b * U_;
#pragma unroll
  for (int j = 0; j < 4; ++j) {
    const int u = w * 64 + j * 16 + lr;
    qv[j] = qpb[u];
    vv[j] = V[u];
  }

  // fused-context accumulators: lane owns d-chunk (w*8 + (lane&7)), 8 floats
  float wacc[8];
#pragma unroll
  for (int d = 0; d < 8; ++d) wacc[d] = 0.f;
  float denl = 0.f;  // wave 0: per-lane (=per-row) weight accumulator

  // ---- prologue: stage tile 0 into buffer 0 (4 batches of 2 rows) ----
#pragma unroll 1
  for (int p = 0; p < 4; ++p) {
    const int r0 = (2 * p) * 8 + w;
    const int r1 = (2 * p + 1) * 8 + w;
    const float* rp0 = vbase + (size_t)r0 * D_ + lane * 8;
    const float* rp1 = vbase + (size_t)r1 * D_ + lane * 8;
    const float4 s0 = *(const float4*)rp0;
    const float4 s1 = *(const float4*)(rp0 + 4);
    const float4 s2 = *(const float4*)rp1;
    const float4 s3 = *(const float4*)(rp1 + 4);
    *(uint4*)&As[r0 * 512 + cw * 8] = pack8(s0, s1);
    *(uint4*)&As[r1 * 512 + cw * 8] = pack8(s2, s3);
  }
  __syncthreads();

  for (int n = 0; n < 8; ++n) {
    const int cur = n & 1;
    const unsigned short* Asc = As + cur * 32768;
    unsigned short* Asn = As + (cur ^ 1) * 32768;
    const float* tb = vbase + (size_t)(n + 1) * 64 * D_;
    const bool pf = (n < 7);

    floatx4 acc[4][4];
#pragma unroll
    for (int i = 0; i < 4; ++i)
#pragma unroll
      for (int j = 0; j < 4; ++j) acc[i][j] = (floatx4)0.f;

    // ---- 4 phases: {issue 2-row prefetch | K-quarter | write 2 rows} ----
#pragma unroll 1
    for (int p = 0; p < 4; ++p) {
      const int r0 = (2 * p) * 8 + w;
      const int r1 = (2 * p + 1) * 8 + w;
      float4 s0, s1, s2, s3;
      if (pf) {
        const float* rp0 = tb + (size_t)r0 * D_ + lane * 8;
        const float* rp1 = tb + (size_t)r1 * D_ + lane * 8;
        s0 = *(const float4*)rp0;
        s1 = *(const float4*)(rp0 + 4);
        s2 = *(const float4*)rp1;
        s3 = *(const float4*)(rp1 + 4);
      }

      // K-quarter: ks = 4p .. 4p+3 (runtime loop: no cross-iter hoisting)
#pragma unroll 1
      for (int kq = 0; kq < 4; ++kq) {
        const int ks = p * 4 + kq;
        const int c = (ks * 4 + kc) ^ (lr & 7);   // row ri&7 == lr&7 for all i
        bf16x8 af[4];
#pragma unroll
        for (int i = 0; i < 4; ++i)
          af[i] = __builtin_bit_cast(
              bf16x8, *(const ushortx8*)&Asc[(i * 16 + lr) * 512 + c * 8]);
#pragma unroll
        for (int j = 0; j < 4; ++j) {
          const bf16x8 bfr = __builtin_bit_cast(
              bf16x8, W2Bv[((w4 + j) * 16 + ks) * 64 + lane]);
#pragma unroll
          for (int i = 0; i < 4; ++i)
            acc[i][j] = __builtin_amdgcn_mfma_f32_16x16x32_bf16(
                af[i], bfr, acc[i][j], 0, 0, 0);
        }
      }

      if (pf) {
        *(uint4*)&Asn[r0 * 512 + cw * 8] = pack8(s0, s1);
        *(uint4*)&Asn[r1 * 512 + cw * 8] = pack8(s2, s3);
      }
    }

    // epilogue partials: C/D layout u = w*64+j*16+lr, t = i*16+kc*4+r
#pragma unroll
    for (int i = 0; i < 4; ++i) {
#pragma unroll
      for (int r = 0; r < 4; ++r) {
        float s = 0.f;
#pragma unroll
        for (int j = 0; j < 4; ++j) s += tanh_fast(acc[i][j][r] + qv[j]) * vv[j];
        s += __shfl_xor(s, 1);
        s += __shfl_xor(s, 2);
        s += __shfl_xor(s, 4);
        s += __shfl_xor(s, 8);
        if (lr == 0) redp[cur * 512 + w * 64 + i * 16 + kc * 4 + r] = s;
      }
    }

    __syncthreads();  // b1: redp + next-tile writes visible; cur reads done

    // per-row weight (row = lane), computed redundantly by every wave
    float sw = redp[cur * 512 + lane];
#pragma unroll
    for (int p = 1; p < 8; ++p) sw += redp[cur * 512 + p * 64 + lane];
    const float wgt = expf(sw);
    if (w == 0) denl += wgt;

    // fused context: wacc[d] += w_r * v[r][d] from the bf16 tile in LDS.
    // lane covers chunk (w*8 + (lane&7)); rows r = (lane>>3) + 8*jj.
#pragma unroll
    for (int jj = 0; jj < 8; ++jj) {
      const int r = (lane >> 3) + 8 * jj;     // r&7 == lane>>3
      const float wr = __shfl(wgt, r);
      const int g = (w * 8 + (lane & 7)) ^ (lane >> 3);
      const ushortx8 vx = *(const ushortx8*)&Asc[r * 512 + g * 8];
#pragma unroll
      for (int d = 0; d < 8; ++d)
        wacc[d] += wr * __uint_as_float((unsigned)vx[d] << 16);
    }

    __syncthreads();  // b2: wsum reads of cur done before n+1 overwrites cur
  }

  // ---- final: reduce wacc over the 8 row-subsets, atomically accumulate ----
#pragma unroll
  for (int d = 0; d < 8; ++d) {
    wacc[d] += __shfl_xor(wacc[d], 8);
    wacc[d] += __shfl_xor(wacc[d], 16);
    wacc[d] += __shfl_xor(wacc[d], 32);
  }
  if (lane < 8) {
    const int d0 = (w * 8 + lane) * 8;
#pragma unroll
    for (int d = 0; d < 8; ++d) atomicAdd(&num[b * D_ + d0 + d], wacc[d]);
  }
  if (w == 0) {
#pragma unroll
    for (int off = 1; off < 64; off <<= 1) denl += __shfl_xor(denl, off);
    if (lane == 0) atomicAdd(&den[b], denl);
  }
}

// ---------------------------------------------------------------------------
// K3: out[b][d] = num[b][d] / den[b]
// ---------------------------------------------------------------------------
__global__ __launch_bounds__(128) void normalize_kernel(
    const float* __restrict__ num, const float* __restrict__ den,
    float* __restrict__ out) {
  const int b = blockIdx.x;
  const float inv = 1.0f / den[b];
  const int d = threadIdx.x * 4;
  float4 v = *(const float4*)&num[b * D_ + d];
  v.x *= inv;
  v.y *= inv;
  v.z *= inv;
  v.w *= inv;
  *(float4*)&out[b * D_ + d] = v;
}

// ---------------------------------------------------------------------------
extern "C" void kernel_launch(void* const* d_in, const int* in_sizes, int n_in,
                              void* d_out, int out_size, void* d_ws,
                              size_t ws_size, hipStream_t stream) {
  const float* query = (const float*)d_in[0];
  const float* values = (const float*)d_in[1];
  const float* W1 = (const float*)d_in[2];
  const float* b1 = (const float*)d_in[3];
  const float* W2 = (const float*)d_in[4];
  const float* b2 = (const float*)d_in[5];
  const float* V = (const float*)d_in[6];
  // d_in[7] = bv : dropped (softmax shift-invariant; cancels in context)

  // ws layout: qp (64 KB) | W2B bf16 packed (512 KB) | num (64 KB) | den (128 B)
  float* qp = (float*)d_ws;
  unsigned short* W2B = (unsigned short*)(qp + (size_t)B_ * U_);
  float* num = (float*)(W2B + (size_t)U_ * D_);
  float* den = num + (size_t)B_ * D_;
  float* out = (float*)d_out;

  (void)hipMemsetAsync(num, 0, ((size_t)B_ * D_ + B_) * sizeof(float), stream);

  prep_w2b<<<128, 256, 0, stream>>>(W2, W2B);
  qproj_kernel<<<dim3(B_, 8), 256, 0, stream>>>(query, W1, b1, b2, qp);
  scores_mfma<<<dim3(8, B_), 512, 0, stream>>>(values, W2B, qp, V, num, den);
  normalize_kernel<<<B_, 128, 0, stream>>>(num, den, out);
}